// Round 8
// baseline (134.519 us; speedup 1.0000x reference)
//
#include <hip/hip_runtime.h>
#include <hip/hip_bf16.h>
#include <stdint.h>

#define BATCH 8192
#define DIM   1024

typedef __attribute__((ext_vector_type(4))) float f32x4;
typedef __attribute__((ext_vector_type(8))) short bf16x8;
typedef __attribute__((ext_vector_type(4))) unsigned short u16x4;
typedef __attribute__((ext_vector_type(8))) unsigned short u16x8;

__device__ __forceinline__ unsigned short f2bf(float f) {
    union { __hip_bfloat16 h; unsigned short u; } v;
    v.h = __hip_bfloat16(f);
    return v.u;
}

__device__ __forceinline__ float sigma_f(float x) {
    float x2 = x * x;
    return x2 * __builtin_amdgcn_rcpf(1.0f + x2);
}

// ---------------------------------------------------------------------------
// Kernel 1: convert A (f32 [D][D]) to bf16
// ---------------------------------------------------------------------------
__global__ __launch_bounds__(256) void convA_kernel(
    const float* __restrict__ A, unsigned short* __restrict__ Ab)
{
    int idx = blockIdx.x * 256 + threadIdx.x;
    f32x4 av = ((const f32x4*)A)[idx];
    u16x4 ab;
#pragma unroll
    for (int i = 0; i < 4; ++i) ab[i] = f2bf(av[i]);
    ((u16x4*)Ab)[idx] = ab;
}

// ---------------------------------------------------------------------------
// Kernel 2: fused, BARRIER-FREE K-loop, register-direct MFMA operands.
//   Per wave: independent 32x64 output tile; A-frag = x rows loaded f32
//   straight from global (sigma in-register), B-frag = A_bf rows straight
//   from global (L2/L3-resident, 2 MB). Register double-buffer (even/odd
//   static sets), NO LDS, NO __syncthreads until the single epilogue barrier.
//   Block = 4 waves (128x64 tile); LDS 32 KiB only for the C-dump so the
//   final streaming pass is fully f32x4-coalesced.
//   XCD swizzle: all 16 bn of one bm land on one XCD -> x rows L2-hit.
// ---------------------------------------------------------------------------
__global__ __launch_bounds__(256, 4) void fused_kernel(
    const float* __restrict__ x, const float* __restrict__ ex,
    const float* __restrict__ W, const float* __restrict__ tgt,
    const unsigned short* __restrict__ Ab,
    float* __restrict__ out0, float* __restrict__ out1,
    float* __restrict__ out2)
{
    __shared__ __align__(16) char lds[32768];    // C f32[128][64] at epilogue

    // ---- block mapping: 16 bn-tiles of each bm co-locate on one XCD
    const int b    = blockIdx.x;
    const int xcd  = b & 7;
    const int idx  = b >> 3;                     // 0..127
    const int bm   = (idx >> 4) * 8 + xcd;       // 0..63
    const int bn   = idx & 15;                   // 0..15

    const int tid  = threadIdx.x;
    const int lane = tid & 63;
    const int wid  = tid >> 6;                   // 0..3 (m-stacked waves)
    const int l15  = lane & 15;
    const int kgo  = (lane >> 4) << 3;           // k-offset within 32-step

    // ---- per-lane fragment base pointers
    const float* gxa0 = x + (size_t)(bm * 128 + wid * 32 + l15) * DIM + kgo;
    const float* gxa1 = gxa0 + (size_t)16 * DIM;
    const unsigned short* gb0 = Ab + (size_t)(bn * 64 + l15) * DIM + kgo;

    f32x4 acc[2][4];
#pragma unroll
    for (int mi = 0; mi < 2; ++mi)
#pragma unroll
        for (int ni = 0; ni < 4; ++ni)
            acc[mi][ni] = f32x4{0.f, 0.f, 0.f, 0.f};

    f32x4 xe[2][2], xo[2][2];
    bf16x8 be[4], bo[4];

    auto LOADX = [&](int kt, f32x4 xa[2][2]) {
        xa[0][0] = *(const f32x4*)(gxa0 + kt * 32);
        xa[0][1] = *(const f32x4*)(gxa0 + kt * 32 + 4);
        xa[1][0] = *(const f32x4*)(gxa1 + kt * 32);
        xa[1][1] = *(const f32x4*)(gxa1 + kt * 32 + 4);
    };
    auto LOADB = [&](int kt, bf16x8 bf[4]) {
#pragma unroll
        for (int ni = 0; ni < 4; ++ni)
            bf[ni] = *(const bf16x8*)(gb0 + (size_t)ni * 16 * DIM + kt * 32);
    };
    auto COMPUTE = [&](f32x4 xa[2][2], bf16x8 bf[4]) {
#pragma unroll
        for (int mi = 0; mi < 2; ++mi) {
            union { u16x8 u; bf16x8 b; } cv;
#pragma unroll
            for (int i = 0; i < 4; ++i) {
                cv.u[i]     = f2bf(sigma_f(xa[mi][0][i]));
                cv.u[i + 4] = f2bf(sigma_f(xa[mi][1][i]));
            }
#pragma unroll
            for (int ni = 0; ni < 4; ++ni)
                acc[mi][ni] = __builtin_amdgcn_mfma_f32_16x16x32_bf16(
                    cv.b, bf[ni], acc[mi][ni], 0, 0, 0);
        }
    };

    // ---- barrier-free K loop, register dbuf (even/odd), prefetch depth 1
    LOADX(0, xe);
    LOADB(0, be);
#pragma unroll
    for (int kt = 0; kt < 32; kt += 2) {
        if (kt + 1 < 32) { LOADX(kt + 1, xo); LOADB(kt + 1, bo); }
        __builtin_amdgcn_sched_barrier(0);
        COMPUTE(xe, be);
        __builtin_amdgcn_sched_barrier(0);
        if (kt + 2 < 32) { LOADX(kt + 2, xe); LOADB(kt + 2, be); }
        __builtin_amdgcn_sched_barrier(0);
        COMPUTE(xo, bo);
        __builtin_amdgcn_sched_barrier(0);
    }

    // ---- epilogue: acc -> LDS C f32[128][64] (2-way bank alias only)
#pragma unroll
    for (int mi = 0; mi < 2; ++mi)
#pragma unroll
        for (int ni = 0; ni < 4; ++ni) {
            const int row_ = wid * 32 + mi * 16 + ((lane >> 4) << 2);
            const int colb = (ni * 16 + l15) * 4;
#pragma unroll
            for (int r = 0; r < 4; ++r)
                *(float*)(lds + (row_ + r) * 256 + colb) = acc[mi][ni][r];
        }
    __syncthreads();

    // ---- streaming pass: row-major, fully vectorized (8 v4 per thread)
#pragma unroll
    for (int p = 0; p < 8; ++p) {
        const int ci  = tid + p * 256;           // 0..2047
        const int row = ci >> 4;                 // 0..127
        const int cv  = ci & 15;                 // f32x4 col index
        f32x4 c = *(const f32x4*)(lds + row * 256 + cv * 16);
        const size_t v4 = (size_t)(bm * 128 + row) * (DIM / 4) + bn * 16 + cv;
        f32x4 xv = ((const f32x4*)x)[v4];
        f32x4 ev = ((const f32x4*)ex)[v4];
        f32x4 wv = ((const f32x4*)W)[v4];
        f32x4 tv = ((const f32x4*)tgt)[bn * 16 + cv];
        f32x4 o0;
#pragma unroll
        for (int e = 0; e < 4; ++e) {
            float xi = xv[e], ti = tv[e];
            float ba = ti * ti * __builtin_amdgcn_rcpf(1.0f + ti * ti);
            float u  = -(wv[e] * (xi + ev[e] - ti)) * ba;
            float s  = sigma_f(xi);
            o0[e] = -xi + u * s + c[e];
        }
        ((f32x4*)out0)[v4] = o0;
        ((f32x4*)out1)[v4] = -o0;
        ((f32x4*)out2)[v4] = f32x4{0.f, 0.f, 0.f, 0.f};
    }
}

// ---------------------------------------------------------------------------
extern "C" void kernel_launch(void* const* d_in, const int* in_sizes, int n_in,
                              void* d_out, int out_size, void* d_ws, size_t ws_size,
                              hipStream_t stream)
{
    const float* x   = (const float*)d_in[0];
    const float* ex  = (const float*)d_in[1];
    const float* W   = (const float*)d_in[2];
    const float* A   = (const float*)d_in[3];
    const float* tgt = (const float*)d_in[4];

    float* out0 = (float*)d_out;
    float* out1 = out0 + (size_t)BATCH * DIM;
    float* out2 = out1 + (size_t)BATCH * DIM;

    unsigned short* Abf = (unsigned short*)d_ws;   // 2 MiB

    convA_kernel<<<DIM * DIM / 4 / 256, 256, 0, stream>>>(A, Abf);
    fused_kernel<<<(BATCH / 128) * (DIM / 64), 256, 0, stream>>>(
        x, ex, W, tgt, Abf, out0, out1, out2);
}

// Round 9
// 65.283 us; speedup vs baseline: 2.0606x; 2.0606x over previous
//
#include <hip/hip_runtime.h>
#include <hip/hip_bf16.h>
#include <stdint.h>

#define BATCH 8192
#define DIM   1024
#define BMT 128            // rows per block tile
#define BNT 64             // cols per tile (two tiles per block)
#define BK  64
#define NT  (DIM / BK)     // 16

typedef __attribute__((ext_vector_type(4))) float f32x4;
typedef __attribute__((ext_vector_type(8))) short bf16x8;
typedef __attribute__((ext_vector_type(4))) unsigned short u16x4;
typedef __attribute__((ext_vector_type(8))) unsigned short u16x8;

#define AS1(p) ((const __attribute__((address_space(1))) void*)(p))
#define AS3(p) ((__attribute__((address_space(3))) void*)(p))

__device__ __forceinline__ unsigned short f2bf(float f) {
    union { __hip_bfloat16 h; unsigned short u; } v;
    v.h = __hip_bfloat16(f);
    return v.u;
}

__device__ __forceinline__ float sigma_f(float x) {
    float x2 = x * x;
    return x2 * __builtin_amdgcn_rcpf(1.0f + x2);
}

// ---------------------------------------------------------------------------
// Kernel 1: convert A (f32 [D][D]) to bf16
// ---------------------------------------------------------------------------
__global__ __launch_bounds__(256) void convA_kernel(
    const float* __restrict__ A, unsigned short* __restrict__ Ab)
{
    int idx = blockIdx.x * 256 + threadIdx.x;
    f32x4 av = ((const f32x4*)A)[idx];
    u16x4 ab;
#pragma unroll
    for (int i = 0; i < 4; ++i) ab[i] = f2bf(av[i]);
    ((u16x4*)Ab)[idx] = ab;
}

// ---------------------------------------------------------------------------
// Kernel 2: fused, TWO 128x64 tiles per block; K-loop || streaming overlap.
//   256 threads (4 waves, 2x2: 64x32/wave, acc[4][2]).
//   LDS 80 KiB -> 2 blocks/CU: staging dbuf 2 x {As 16K | Bs 8K} = 48K,
//   C f32[128][64] = 32K at +49152.
//   P0: K-loop(bn0) + out2-zero stores interleaved (useful BW under latency).
//   P1: K-loop(bn1) + epilogue(bn0) interleaved (loads early, stores late).
//   P2: epilogue(bn1).
//   Co-resident blocks are barrier-decoupled -> phases interleave across
//   blocks too (P2 streaming covers the other block's P0 stalls).
// ---------------------------------------------------------------------------
__global__ __launch_bounds__(256, 2) void fused_kernel(
    const float* __restrict__ x, const float* __restrict__ ex,
    const float* __restrict__ W, const float* __restrict__ tgt,
    const unsigned short* __restrict__ Ab,
    float* __restrict__ out0, float* __restrict__ out1,
    float* __restrict__ out2)
{
    __shared__ __align__(16) char lds[81920];
    char* Cl = lds + 49152;                      // C f32[128][64], swizzled

    // ---- block mapping: 8 bms per XCD (x slice 4 MB = one L2)
    const int b     = blockIdx.x;
    const int xcd   = b & 7;
    const int local = b >> 3;                    // 0..63
    const int bm    = xcd * 8 + (local >> 3);    // 0..63
    const int bn0   = (local & 7) * 2;           // 0,2,..,14
    const int bn1   = bn0 + 1;

    const int tid  = threadIdx.x;
    const int lane = tid & 63;
    const int wid  = tid >> 6;                   // 0..3
    const int wr   = wid >> 1;                   // 0..1
    const int wc   = wid & 1;                    // 0..1
    const int l15  = lane & 15;

    // ---- B staging (global_load_lds, pre-swizzled source, linear LDS dest)
    const int swz = (((lane & 7) ^ (lane >> 3)) << 4);
    const char* gBb = (const char*)Ab +
        ((size_t)(wid * 8 + (lane >> 3)) * DIM) * 2 + swz;

    // ---- A(sigma) staging: thread -> rows r0+32s (s=0..3), col group g
    const int r0 = tid >> 3;                     // 0..31
    const int g  = tid & 7;
    const float* gx = x + (size_t)(bm * BMT + r0) * DIM + g * 8;
    const int wAoff = (g * 16) ^ ((r0 & 7) << 4);

    // ---- fragment read constants
    const int rd_sw = (lane & 7) << 4;
    const int cb0   = (lane >> 4) << 4;

    f32x4 acc[4][2];

    auto accZero = [&]() {
#pragma unroll
        for (int mi = 0; mi < 4; ++mi)
#pragma unroll
            for (int ni = 0; ni < 2; ++ni)
                acc[mi][ni] = f32x4{0.f, 0.f, 0.f, 0.f};
    };
    auto stageB = [&](int bn, int k, char* Bs) {
        const char* gB = gBb + (size_t)bn * (BNT * DIM * 2) + (size_t)k * 2;
#pragma unroll
        for (int j = 0; j < 2; ++j)
            __builtin_amdgcn_global_load_lds(
                AS1(gB + (size_t)j * (32 * DIM * 2)),
                AS3(Bs + (wid * 8 + j * 32) * 128), 16, 0, 0);
    };
    auto loadX = [&](int k, f32x4 xa[4][2]) {
#pragma unroll
        for (int s = 0; s < 4; ++s) {
            xa[s][0] = *(const f32x4*)(gx + (size_t)s * 32 * DIM + k);
            xa[s][1] = *(const f32x4*)(gx + (size_t)s * 32 * DIM + k + 4);
        }
    };
    auto writeSig = [&](char* As, f32x4 xa[4][2]) {
#pragma unroll
        for (int s = 0; s < 4; ++s) {
            u16x8 sb;
#pragma unroll
            for (int i = 0; i < 4; ++i) {
                sb[i]     = f2bf(sigma_f(xa[s][0][i]));
                sb[i + 4] = f2bf(sigma_f(xa[s][1][i]));
            }
            *(u16x8*)(As + (r0 + s * 32) * 128 + wAoff) = sb;
        }
    };
    auto mfmaPhase = [&](const char* buf) {
        const char* As_ = buf;
        const char* Bs_ = buf + 16384;
#pragma unroll
        for (int kk = 0; kk < 2; ++kk) {
            bf16x8 af[4], bfr[2];
#pragma unroll
            for (int mi = 0; mi < 4; ++mi)
                af[mi] = *(const bf16x8*)(As_ + (wr * 64 + mi * 16 + l15) * 128 +
                                          ((cb0 + kk * 64) ^ rd_sw));
#pragma unroll
            for (int ni = 0; ni < 2; ++ni)
                bfr[ni] = *(const bf16x8*)(Bs_ + (wc * 32 + ni * 16 + l15) * 128 +
                                           ((cb0 + kk * 64) ^ rd_sw));
#pragma unroll
            for (int mi = 0; mi < 4; ++mi)
#pragma unroll
                for (int ni = 0; ni < 2; ++ni)
                    acc[mi][ni] = __builtin_amdgcn_mfma_f32_16x16x32_bf16(
                        af[mi], bfr[ni], acc[mi][ni], 0, 0, 0);
        }
    };
    auto dumpC = [&]() {
#pragma unroll
        for (int mi = 0; mi < 4; ++mi)
#pragma unroll
            for (int ni = 0; ni < 2; ++ni) {
                const int row_ = wr * 64 + mi * 16 + ((lane >> 4) << 2);
                const int colb = (wc * 32 + ni * 16 + l15) * 4;
#pragma unroll
                for (int r = 0; r < 4; ++r) {
                    const int rr = row_ + r;
                    *(float*)(Cl + rr * 256 + (colb ^ (((rr >> 2) & 7) << 4))) =
                        acc[mi][ni][r];
                }
            }
    };

    accZero();

    // ================= P0: K-loop(bn0) + out2 zeros =========================
    {
        f32x4 xa[4][2];
        loadX(0, xa);
        stageB(bn0, 0, lds + 16384);
        writeSig(lds, xa);
    }
    __syncthreads();

    for (int t = 0; t < NT; ++t) {
        const int cur = t & 1;
        char* bufn = lds + (cur ^ 1) * 24576;
        f32x4 xa[4][2];
        if (t + 1 < NT) {
            loadX((t + 1) * BK, xa);
            stageB(bn0, (t + 1) * BK, bufn + 16384);
        }
        // out2 zeros: 1 f32x4/thread/iter covers both tiles (128 cols)
        {
            const int j   = t * 256 + tid;       // 0..4095
            const int row = j >> 5;              // 0..127
            const int cvv = j & 31;              // 0..31 (128 cols)
            ((f32x4*)out2)[(size_t)(bm * BMT + row) * (DIM / 4) + bn0 * 16 + cvv] =
                f32x4{0.f, 0.f, 0.f, 0.f};
        }
        __builtin_amdgcn_sched_barrier(0);
        mfmaPhase(lds + cur * 24576);
        __builtin_amdgcn_sched_barrier(0);
        if (t + 1 < NT) writeSig(bufn, xa);
        __syncthreads();
    }

    // ---- dump C(bn0); prologue bn1 (the trailing sync publishes C too)
    dumpC();
    accZero();
    {
        f32x4 xa[4][2];
        loadX(0, xa);
        stageB(bn1, 0, lds + 16384);
        writeSig(lds, xa);
    }
    __syncthreads();

    // ================= P1: K-loop(bn1) + epilogue(bn0) ======================
    for (int t = 0; t < NT; ++t) {
        const int cur = t & 1;
        char* bufn = lds + (cur ^ 1) * 24576;
        f32x4 xa[4][2];
        if (t + 1 < NT) {
            loadX((t + 1) * BK, xa);
            stageB(bn1, (t + 1) * BK, bufn + 16384);
        }
        f32x4 eC, eX, eE, eW, eT;
        size_t ev4 = 0;
        const bool doEpi = (t & 1);
        if (doEpi) {
            const int pp  = t >> 1;              // 0..7
            const int ci  = pp * 256 + tid;      // 0..2047
            const int row = ci >> 4;             // 0..127
            const int cv  = ci & 15;             // 0..15
            eC = *(const f32x4*)(Cl + row * 256 +
                                 ((cv * 16) ^ (((row >> 2) & 7) << 4)));
            ev4 = (size_t)(bm * BMT + row) * (DIM / 4) + bn0 * 16 + cv;
            eX = ((const f32x4*)x)[ev4];
            eE = ((const f32x4*)ex)[ev4];
            eW = ((const f32x4*)W)[ev4];
            eT = ((const f32x4*)tgt)[bn0 * 16 + cv];
        }
        __builtin_amdgcn_sched_barrier(0);
        mfmaPhase(lds + cur * 24576);
        __builtin_amdgcn_sched_barrier(0);
        if (t + 1 < NT) writeSig(bufn, xa);
        if (doEpi) {
            f32x4 o0;
#pragma unroll
            for (int e = 0; e < 4; ++e) {
                float xi = eX[e], ti = eT[e];
                float ba = ti * ti * __builtin_amdgcn_rcpf(1.0f + ti * ti);
                float u  = -(eW[e] * (xi + eE[e] - ti)) * ba;
                float s  = sigma_f(xi);
                o0[e] = -xi + u * s + eC[e];
            }
            ((f32x4*)out0)[ev4] = o0;
            ((f32x4*)out1)[ev4] = -o0;
        }
        __syncthreads();
    }

    // ================= P2: epilogue(bn1) ====================================
    dumpC();
    __syncthreads();

#pragma unroll
    for (int pp = 0; pp < 8; ++pp) {
        const int ci  = pp * 256 + tid;
        const int row = ci >> 4;
        const int cv  = ci & 15;
        f32x4 c = *(const f32x4*)(Cl + row * 256 +
                                  ((cv * 16) ^ (((row >> 2) & 7) << 4)));
        const size_t v4 = (size_t)(bm * BMT + row) * (DIM / 4) + bn1 * 16 + cv;
        f32x4 xv = ((const f32x4*)x)[v4];
        f32x4 ev = ((const f32x4*)ex)[v4];
        f32x4 wv = ((const f32x4*)W)[v4];
        f32x4 tv = ((const f32x4*)tgt)[bn1 * 16 + cv];
        f32x4 o0;
#pragma unroll
        for (int e = 0; e < 4; ++e) {
            float xi = xv[e], ti = tv[e];
            float ba = ti * ti * __builtin_amdgcn_rcpf(1.0f + ti * ti);
            float u  = -(wv[e] * (xi + ev[e] - ti)) * ba;
            float s  = sigma_f(xi);
            o0[e] = -xi + u * s + c[e];
        }
        ((f32x4*)out0)[v4] = o0;
        ((f32x4*)out1)[v4] = -o0;
    }
}

// ---------------------------------------------------------------------------
extern "C" void kernel_launch(void* const* d_in, const int* in_sizes, int n_in,
                              void* d_out, int out_size, void* d_ws, size_t ws_size,
                              hipStream_t stream)
{
    const float* x   = (const float*)d_in[0];
    const float* ex  = (const float*)d_in[1];
    const float* W   = (const float*)d_in[2];
    const float* A   = (const float*)d_in[3];
    const float* tgt = (const float*)d_in[4];

    float* out0 = (float*)d_out;
    float* out1 = out0 + (size_t)BATCH * DIM;
    float* out2 = out1 + (size_t)BATCH * DIM;

    unsigned short* Abf = (unsigned short*)d_ws;   // 2 MiB

    convA_kernel<<<DIM * DIM / 4 / 256, 256, 0, stream>>>(A, Abf);
    fused_kernel<<<(BATCH / BMT) * (DIM / BNT) / 2, 256, 0, stream>>>(
        x, ex, W, tgt, Abf, out0, out1, out2);
}